// Round 2
// baseline (493.350 us; speedup 1.0000x reference)
//
#include <hip/hip_runtime.h>

#define TPB 256
#define EPB 32   // elements per block; 8 lanes per element

typedef float f32x4 __attribute__((ext_vector_type(4)));

__device__ __forceinline__ float sigm(float x) {
    return __builtin_amdgcn_rcpf(1.0f + __builtin_amdgcn_exp2f(-1.44269504f * x));
}
__device__ __forceinline__ float tanh_fast(float x) {
    float e = __builtin_amdgcn_exp2f(-2.88539008f * x);
    return (1.0f - e) * __builtin_amdgcn_rcpf(1.0f + e);
}

// lane->lane XOR shuffle within 32-lane halves via ds_swizzle (BitMode: xor<<10 | and 0x1F)
#define SWZ(v, m) __int_as_float(__builtin_amdgcn_ds_swizzle(__float_as_int(v), ((m) << 10) | 31))

// per-lane weight block in sSeg, stride 100 floats per j:
//   [g*16 + d]        wih[g][d]       (d padded to 16; layer0 col15 = 0)
//   [64 + g*8 + m]    whx[g][m] = Whh[row][j^m]   (pre-permuted for XOR shuffles)
//   [96 + g]          bias[g]
__device__ __forceinline__ void build_seg(int l, int dir,
                                          const float* __restrict__ Wih0,
                                          const float* __restrict__ Wih_rest,
                                          const float* __restrict__ Whh,
                                          const float* __restrict__ bW,
                                          float* sSeg, int tid)
{
    for (int i = tid; i < 800; i += TPB) {
        int j = i / 100, r = i % 100;
        float v;
        if (r < 64) {
            int g = r >> 4, d = r & 15, row = g * 8 + j;
            if (l == 0) v = (d < 15) ? Wih0[dir * 480 + row * 15 + d] : 0.0f;
            else        v = Wih_rest[((l - 1) * 2 + dir) * 512 + row * 16 + d];
        } else if (r < 96) {
            int rr = r - 64, g = rr >> 3, m = rr & 7, row = g * 8 + j;
            v = Whh[(l * 2 + dir) * 256 + row * 8 + (j ^ m)];
        } else {
            int g = r - 96, row = g * 8 + j;
            v = bW[(l * 2 + dir) * 32 + row];
        }
        sSeg[i] = v;
    }
}

#define KEEP(v) asm volatile("" : "+v"(v))

template<int DIR, bool LAST>
__device__ __forceinline__ void run_seg(const float* cur, float* nxt, const float* sSeg,
                                        const float* __restrict__ Wout,
                                        float& acc, int el, int j)
{
    const f32x4* wp = (const f32x4*)&sSeg[j * 100];
    f32x4 wi[16], wh[8], wb;
    #pragma unroll
    for (int q = 0; q < 16; ++q) wi[q] = wp[q];
    #pragma unroll
    for (int q = 0; q < 8; ++q)  wh[q] = wp[16 + q];
    wb = wp[24];
    // pin in VGPRs: the asm "modifies" the values, so the compiler cannot
    // rematerialize the LDS loads inside the timestep loop.
    KEEP(wi[0]);  KEEP(wi[1]);  KEEP(wi[2]);  KEEP(wi[3]);
    KEEP(wi[4]);  KEEP(wi[5]);  KEEP(wi[6]);  KEEP(wi[7]);
    KEEP(wi[8]);  KEEP(wi[9]);  KEEP(wi[10]); KEEP(wi[11]);
    KEEP(wi[12]); KEEP(wi[13]); KEEP(wi[14]); KEEP(wi[15]);
    KEEP(wh[0]);  KEEP(wh[1]);  KEEP(wh[2]);  KEEP(wh[3]);
    KEEP(wh[4]);  KEEP(wh[5]);  KEEP(wh[6]);  KEEP(wh[7]);
    KEEP(wb);

    float hn = 0.0f, cst = 0.0f;
    #pragma unroll 2
    for (int tt = 0; tt < 10; ++tt) {
        const int s = DIR ? (9 - tt) : tt;
        const f32x4* xp = (const f32x4*)&cur[(s * EPB + el) * 16];
        f32x4 x0 = xp[0], x1 = xp[1], x2 = xp[2], x3 = xp[3];

        // broadcast previous h across the 8-lane group (independent swizzles)
        float h1 = SWZ(hn, 1), h2 = SWZ(hn, 2), h3 = SWZ(hn, 3), h4 = SWZ(hn, 4),
              h5 = SWZ(hn, 5), h6 = SWZ(hn, 6), h7 = SWZ(hn, 7);

        float g0 = wb[0]
            + wi[0][0]*x0[0] + wi[0][1]*x0[1] + wi[0][2]*x0[2] + wi[0][3]*x0[3]
            + wi[1][0]*x1[0] + wi[1][1]*x1[1] + wi[1][2]*x1[2] + wi[1][3]*x1[3]
            + wi[2][0]*x2[0] + wi[2][1]*x2[1] + wi[2][2]*x2[2] + wi[2][3]*x2[3]
            + wi[3][0]*x3[0] + wi[3][1]*x3[1] + wi[3][2]*x3[2] + wi[3][3]*x3[3]
            + wh[0][0]*hn + wh[0][1]*h1 + wh[0][2]*h2 + wh[0][3]*h3
            + wh[1][0]*h4 + wh[1][1]*h5 + wh[1][2]*h6 + wh[1][3]*h7;
        float g1 = wb[1]
            + wi[4][0]*x0[0] + wi[4][1]*x0[1] + wi[4][2]*x0[2] + wi[4][3]*x0[3]
            + wi[5][0]*x1[0] + wi[5][1]*x1[1] + wi[5][2]*x1[2] + wi[5][3]*x1[3]
            + wi[6][0]*x2[0] + wi[6][1]*x2[1] + wi[6][2]*x2[2] + wi[6][3]*x2[3]
            + wi[7][0]*x3[0] + wi[7][1]*x3[1] + wi[7][2]*x3[2] + wi[7][3]*x3[3]
            + wh[2][0]*hn + wh[2][1]*h1 + wh[2][2]*h2 + wh[2][3]*h3
            + wh[3][0]*h4 + wh[3][1]*h5 + wh[3][2]*h6 + wh[3][3]*h7;
        float g2 = wb[2]
            + wi[8][0]*x0[0] + wi[8][1]*x0[1] + wi[8][2]*x0[2] + wi[8][3]*x0[3]
            + wi[9][0]*x1[0] + wi[9][1]*x1[1] + wi[9][2]*x1[2] + wi[9][3]*x1[3]
            + wi[10][0]*x2[0] + wi[10][1]*x2[1] + wi[10][2]*x2[2] + wi[10][3]*x2[3]
            + wi[11][0]*x3[0] + wi[11][1]*x3[1] + wi[11][2]*x3[2] + wi[11][3]*x3[3]
            + wh[4][0]*hn + wh[4][1]*h1 + wh[4][2]*h2 + wh[4][3]*h3
            + wh[5][0]*h4 + wh[5][1]*h5 + wh[5][2]*h6 + wh[5][3]*h7;
        float g3 = wb[3]
            + wi[12][0]*x0[0] + wi[12][1]*x0[1] + wi[12][2]*x0[2] + wi[12][3]*x0[3]
            + wi[13][0]*x1[0] + wi[13][1]*x1[1] + wi[13][2]*x1[2] + wi[13][3]*x1[3]
            + wi[14][0]*x2[0] + wi[14][1]*x2[1] + wi[14][2]*x2[2] + wi[14][3]*x2[3]
            + wi[15][0]*x3[0] + wi[15][1]*x3[1] + wi[15][2]*x3[2] + wi[15][3]*x3[3]
            + wh[6][0]*hn + wh[6][1]*h1 + wh[6][2]*h2 + wh[6][3]*h3
            + wh[7][0]*h4 + wh[7][1]*h5 + wh[7][2]*h6 + wh[7][3]*h7;

        const float ig = sigm(g0), fg = sigm(g1);
        const float gg = tanh_fast(g2), og = sigm(g3);
        cst = fg * cst + ig * gg;
        hn = og * tanh_fast(cst);

        if (LAST) {
            acc += hn * Wout[s * 16 + DIR * 8 + j];
        } else {
            nxt[(s * EPB + el) * 16 + DIR * 8 + j] = hn;
        }
    }
}

__global__ __launch_bounds__(TPB, 3)
void lstm_kernel(const float* __restrict__ x,
                 const float* __restrict__ Wih0,
                 const float* __restrict__ Wih_rest,
                 const float* __restrict__ Whh,
                 const float* __restrict__ bW,
                 const float* __restrict__ Wout,
                 const float* __restrict__ bout,
                 float* __restrict__ out)
{
    __shared__ __align__(16) float bufA[5120];   // [t=10][e=32][16]
    __shared__ __align__(16) float bufB[5120];
    __shared__ __align__(16) float sSeg[800];    // per-segment per-lane weights

    const int tid = threadIdx.x;

    // ---- stage x (coalesced read): x[b][c][t][d] -> bufA[t][e][c*5+d], pad col 15 ----
    const float* xblk = x + (size_t)blockIdx.x * (EPB * 150);
    for (int i = tid; i < EPB * 150; i += TPB) {
        int e = i / 150, r = i % 150;
        int c = r / 50, r2 = r % 50, t = r2 / 5, d = r2 % 5;
        bufA[(t * EPB + e) * 16 + c * 5 + d] = xblk[i];
    }
    for (int i = tid; i < 320; i += TPB) {
        int t = i >> 5, e = i & 31;
        bufA[(t * EPB + e) * 16 + 15] = 0.0f;
    }

    const int lane = tid & 63;
    const int wid  = tid >> 6;
    const int grp  = lane >> 3;
    const int j    = lane & 7;
    const int el   = wid * 8 + grp;

    float acc = 0.0f;

    // layer 0: bufA -> bufB
    build_seg(0, 0, Wih0, Wih_rest, Whh, bW, sSeg, tid);
    __syncthreads();
    run_seg<0, false>(bufA, bufB, sSeg, Wout, acc, el, j);
    __syncthreads();
    build_seg(0, 1, Wih0, Wih_rest, Whh, bW, sSeg, tid);
    __syncthreads();
    run_seg<1, false>(bufA, bufB, sSeg, Wout, acc, el, j);
    __syncthreads();

    // layer 1: bufB -> bufA
    build_seg(1, 0, Wih0, Wih_rest, Whh, bW, sSeg, tid);
    __syncthreads();
    run_seg<0, false>(bufB, bufA, sSeg, Wout, acc, el, j);
    __syncthreads();
    build_seg(1, 1, Wih0, Wih_rest, Whh, bW, sSeg, tid);
    __syncthreads();
    run_seg<1, false>(bufB, bufA, sSeg, Wout, acc, el, j);
    __syncthreads();

    // layer 2: bufA -> acc
    build_seg(2, 0, Wih0, Wih_rest, Whh, bW, sSeg, tid);
    __syncthreads();
    run_seg<0, true>(bufA, bufB, sSeg, Wout, acc, el, j);
    __syncthreads();
    build_seg(2, 1, Wih0, Wih_rest, Whh, bW, sSeg, tid);
    __syncthreads();
    run_seg<1, true>(bufA, bufB, sSeg, Wout, acc, el, j);

    // reduce the 8 lanes of the group -> scalar output
    acc += __shfl_xor(acc, 1);
    acc += __shfl_xor(acc, 2);
    acc += __shfl_xor(acc, 4);
    if (j == 0) {
        out[(size_t)blockIdx.x * EPB + el] = acc + bout[0];
    }
}

extern "C" void kernel_launch(void* const* d_in, const int* in_sizes, int n_in,
                              void* d_out, int out_size, void* d_ws, size_t ws_size,
                              hipStream_t stream) {
    const float* x        = (const float*)d_in[0];
    const float* Wih0     = (const float*)d_in[1];
    const float* Wih_rest = (const float*)d_in[2];
    const float* Whh      = (const float*)d_in[3];
    const float* b        = (const float*)d_in[4];
    const float* Wout     = (const float*)d_in[5];
    const float* bout     = (const float*)d_in[6];
    float* out = (float*)d_out;

    const int nblocks = out_size / EPB;  // 262144 / 32 = 8192
    lstm_kernel<<<nblocks, TPB, 0, stream>>>(x, Wih0, Wih_rest, Whh, b, Wout, bout, out);
}

// Round 3
// 492.773 us; speedup vs baseline: 1.0012x; 1.0012x over previous
//
#include <hip/hip_runtime.h>

#define TPB 256
#define EPB 32   // elements per block; 8 lanes per element

typedef float f32x2 __attribute__((ext_vector_type(2)));
typedef float f32x4 __attribute__((ext_vector_type(4)));

__device__ __forceinline__ float sigm(float x) {
    return __builtin_amdgcn_rcpf(1.0f + __builtin_amdgcn_exp2f(-1.44269504f * x));
}
__device__ __forceinline__ float tanh_fast(float x) {
    float e = __builtin_amdgcn_exp2f(-2.88539008f * x);
    return (1.0f - e) * __builtin_amdgcn_rcpf(1.0f + e);
}

// lane->lane XOR shuffle within 32-lane halves via ds_swizzle (BitMode: xor<<10 | and 0x1F)
#define SWZ(v, m) __int_as_float(__builtin_amdgcn_ds_swizzle(__float_as_int(v), ((m) << 10) | 31))

// packed f32 FMA: acc(2) += w(2) * x(2), full f32 precision, one VALU issue slot
#define PKFMA(acc, w, xx) asm("v_pk_fma_f32 %0, %1, %2, %0" : "+v"(acc) : "v"(w), "v"(xx))

// per-lane weight block in sSeg, stride 100 floats per j:
//   [g*16 + d]        wih[g][d]       (d padded to 16; layer0 col15 = 0)
//   [64 + g*8 + m]    whx[g][m] = Whh[row][j^m]   (pre-permuted for XOR shuffles)
//   [96 + g]          bias[g]
__device__ __forceinline__ void build_seg(int l, int dir,
                                          const float* __restrict__ Wih0,
                                          const float* __restrict__ Wih_rest,
                                          const float* __restrict__ Whh,
                                          const float* __restrict__ bW,
                                          float* __restrict__ sSeg, int tid)
{
    for (int i = tid; i < 800; i += TPB) {
        int j = i / 100, r = i % 100;
        float v;
        if (r < 64) {
            int g = r >> 4, d = r & 15, row = g * 8 + j;
            if (l == 0) v = (d < 15) ? Wih0[dir * 480 + row * 15 + d] : 0.0f;
            else        v = Wih_rest[((l - 1) * 2 + dir) * 512 + row * 16 + d];
        } else if (r < 96) {
            int rr = r - 64, g = rr >> 3, m = rr & 7, row = g * 8 + j;
            v = Whh[(l * 2 + dir) * 256 + row * 8 + (j ^ m)];
        } else {
            int g = r - 96, row = g * 8 + j;
            v = bW[(l * 2 + dir) * 32 + row];
        }
        sSeg[i] = v;
    }
}

template<int DIR, bool LAST>
__device__ __forceinline__ void run_seg(const float* __restrict__ cur,
                                        float* __restrict__ nxt,
                                        const float* __restrict__ sSeg,
                                        const float* __restrict__ Wout,
                                        float& acc, int el, int j)
{
    // weights as f32x2 pairs along the reduction dim; loop-invariant (restrict)
    const f32x2* wp = (const f32x2*)&sSeg[j * 100];
    f32x2 wx0[8], wx1[8], wx2[8], wx3[8];
    f32x2 wh0[4], wh1[4], wh2[4], wh3[4];
    #pragma unroll
    for (int q = 0; q < 8; ++q) {
        wx0[q] = wp[q]; wx1[q] = wp[8 + q]; wx2[q] = wp[16 + q]; wx3[q] = wp[24 + q];
    }
    #pragma unroll
    for (int q = 0; q < 4; ++q) {
        wh0[q] = wp[32 + q]; wh1[q] = wp[36 + q]; wh2[q] = wp[40 + q]; wh3[q] = wp[44 + q];
    }
    const float b0 = sSeg[j * 100 + 96], b1 = sSeg[j * 100 + 97];
    const float b2 = sSeg[j * 100 + 98], b3 = sSeg[j * 100 + 99];

    float hn = 0.0f, cst = 0.0f;
    #pragma unroll
    for (int tt = 0; tt < 10; ++tt) {
        const int s = DIR ? (9 - tt) : tt;
        const f32x2* xp = (const f32x2*)&cur[(s * EPB + el) * 16];
        f32x2 xv[8];
        #pragma unroll
        for (int q = 0; q < 8; ++q) xv[q] = xp[q];

        // broadcast previous h across the 8-lane group, packed into pairs
        float h1 = SWZ(hn, 1), h2 = SWZ(hn, 2), h3 = SWZ(hn, 3), h4 = SWZ(hn, 4),
              h5 = SWZ(hn, 5), h6 = SWZ(hn, 6), h7 = SWZ(hn, 7);
        f32x2 hp0 = {hn, h1}, hp1 = {h2, h3}, hp2 = {h4, h5}, hp3 = {h6, h7};

        f32x2 a0 = {b0, 0.0f}, a1 = {b1, 0.0f}, a2 = {b2, 0.0f}, a3 = {b3, 0.0f};
        #pragma unroll
        for (int q = 0; q < 8; ++q) {
            PKFMA(a0, wx0[q], xv[q]);
            PKFMA(a1, wx1[q], xv[q]);
            PKFMA(a2, wx2[q], xv[q]);
            PKFMA(a3, wx3[q], xv[q]);
        }
        PKFMA(a0, wh0[0], hp0); PKFMA(a0, wh0[1], hp1); PKFMA(a0, wh0[2], hp2); PKFMA(a0, wh0[3], hp3);
        PKFMA(a1, wh1[0], hp0); PKFMA(a1, wh1[1], hp1); PKFMA(a1, wh1[2], hp2); PKFMA(a1, wh1[3], hp3);
        PKFMA(a2, wh2[0], hp0); PKFMA(a2, wh2[1], hp1); PKFMA(a2, wh2[2], hp2); PKFMA(a2, wh2[3], hp3);
        PKFMA(a3, wh3[0], hp0); PKFMA(a3, wh3[1], hp1); PKFMA(a3, wh3[2], hp2); PKFMA(a3, wh3[3], hp3);

        const float g0 = a0.x + a0.y;
        const float g1 = a1.x + a1.y;
        const float g2 = a2.x + a2.y;
        const float g3 = a3.x + a3.y;

        const float ig = sigm(g0), fg = sigm(g1);
        const float gg = tanh_fast(g2), og = sigm(g3);
        cst = fg * cst + ig * gg;
        hn = og * tanh_fast(cst);

        if (LAST) {
            acc += hn * Wout[s * 16 + DIR * 8 + j];
        } else {
            nxt[(s * EPB + el) * 16 + DIR * 8 + j] = hn;
        }
    }
}

__global__ __launch_bounds__(TPB, 2)
void lstm_kernel(const float* __restrict__ x,
                 const float* __restrict__ Wih0,
                 const float* __restrict__ Wih_rest,
                 const float* __restrict__ Whh,
                 const float* __restrict__ bW,
                 const float* __restrict__ Wout,
                 const float* __restrict__ bout,
                 float* __restrict__ out)
{
    __shared__ __align__(16) float bufA[5120];   // [t=10][e=32][16]
    __shared__ __align__(16) float bufB[5120];
    __shared__ __align__(16) float sSeg[800];    // per-segment per-lane weights

    const int tid = threadIdx.x;

    // ---- stage x (coalesced read): x[b][c][t][d] -> bufA[t][e][c*5+d], pad col 15 ----
    const float* xblk = x + (size_t)blockIdx.x * (EPB * 150);
    for (int i = tid; i < EPB * 150; i += TPB) {
        int e = i / 150, r = i % 150;
        int c = r / 50, r2 = r % 50, t = r2 / 5, d = r2 % 5;
        bufA[(t * EPB + e) * 16 + c * 5 + d] = xblk[i];
    }
    for (int i = tid; i < 320; i += TPB) {
        int t = i >> 5, e = i & 31;
        bufA[(t * EPB + e) * 16 + 15] = 0.0f;
    }

    const int lane = tid & 63;
    const int wid  = tid >> 6;
    const int grp  = lane >> 3;
    const int j    = lane & 7;
    const int el   = wid * 8 + grp;

    float acc = 0.0f;

    // layer 0: bufA -> bufB
    build_seg(0, 0, Wih0, Wih_rest, Whh, bW, sSeg, tid);
    __syncthreads();
    run_seg<0, false>(bufA, bufB, sSeg, Wout, acc, el, j);
    __syncthreads();
    build_seg(0, 1, Wih0, Wih_rest, Whh, bW, sSeg, tid);
    __syncthreads();
    run_seg<1, false>(bufA, bufB, sSeg, Wout, acc, el, j);
    __syncthreads();

    // layer 1: bufB -> bufA
    build_seg(1, 0, Wih0, Wih_rest, Whh, bW, sSeg, tid);
    __syncthreads();
    run_seg<0, false>(bufB, bufA, sSeg, Wout, acc, el, j);
    __syncthreads();
    build_seg(1, 1, Wih0, Wih_rest, Whh, bW, sSeg, tid);
    __syncthreads();
    run_seg<1, false>(bufB, bufA, sSeg, Wout, acc, el, j);
    __syncthreads();

    // layer 2: bufA -> acc
    build_seg(2, 0, Wih0, Wih_rest, Whh, bW, sSeg, tid);
    __syncthreads();
    run_seg<0, true>(bufA, bufB, sSeg, Wout, acc, el, j);
    __syncthreads();
    build_seg(2, 1, Wih0, Wih_rest, Whh, bW, sSeg, tid);
    __syncthreads();
    run_seg<1, true>(bufA, bufB, sSeg, Wout, acc, el, j);

    // reduce the 8 lanes of the group -> scalar output
    acc += __shfl_xor(acc, 1);
    acc += __shfl_xor(acc, 2);
    acc += __shfl_xor(acc, 4);
    if (j == 0) {
        out[(size_t)blockIdx.x * EPB + el] = acc + bout[0];
    }
}

extern "C" void kernel_launch(void* const* d_in, const int* in_sizes, int n_in,
                              void* d_out, int out_size, void* d_ws, size_t ws_size,
                              hipStream_t stream) {
    const float* x        = (const float*)d_in[0];
    const float* Wih0     = (const float*)d_in[1];
    const float* Wih_rest = (const float*)d_in[2];
    const float* Whh      = (const float*)d_in[3];
    const float* b        = (const float*)d_in[4];
    const float* Wout     = (const float*)d_in[5];
    const float* bout     = (const float*)d_in[6];
    float* out = (float*)d_out;

    const int nblocks = out_size / EPB;  // 262144 / 32 = 8192
    lstm_kernel<<<nblocks, TPB, 0, stream>>>(x, Wih0, Wih_rest, Whh, b, Wout, bout, out);
}

// Round 4
// 418.744 us; speedup vs baseline: 1.1782x; 1.1768x over previous
//
#include <hip/hip_runtime.h>

#define TPB 256
#define EPB 32   // elements per block; 8 lanes per element

typedef float f32x2 __attribute__((ext_vector_type(2)));

// lane->lane XOR shuffle within 32-lane halves via ds_swizzle (BitMode: xor<<10 | and 0x1F)
#define SWZ(v, m) __int_as_float(__builtin_amdgcn_ds_swizzle(__float_as_int(v), ((m) << 10) | 31))
// packed f32 FMA (full f32 precision, one issue slot for 2 MACs)
#define PKFMA(acc, w, xx) asm("v_pk_fma_f32 %0, %1, %2, %0" : "+v"(acc) : "v"(w), "v"(xx))

#define L2E 1.44269504f

// per-lane weight block in sSeg, stride 100 floats per j, PRESCALED by
// s_g = (g==2 ? -2*L2E : -L2E)  so gates feed exp2 directly:
//   [g*16 + d]      wih[g][d]   (padded to 16; layer0 col15 = 0)
//   [64 + g*8 + m]  whx[g][m] = s_g * Whh[row][j^m]  (pre-permuted for XOR shuffles)
//   [96 + g]        bias[g] * s_g
__device__ __forceinline__ void build_seg(int l, int dir,
                                          const float* __restrict__ Wih0,
                                          const float* __restrict__ Wih_rest,
                                          const float* __restrict__ Whh,
                                          const float* __restrict__ bW,
                                          float* __restrict__ sSeg, int tid)
{
    for (int i = tid; i < 800; i += TPB) {
        int j = i / 100, r = i % 100;
        float v;
        int g;
        if (r < 64) {
            g = r >> 4;
            int d = r & 15, row = g * 8 + j;
            if (l == 0) v = (d < 15) ? Wih0[dir * 480 + row * 15 + d] : 0.0f;
            else        v = Wih_rest[((l - 1) * 2 + dir) * 512 + row * 16 + d];
        } else if (r < 96) {
            int rr = r - 64;
            g = rr >> 3;
            int m = rr & 7, row = g * 8 + j;
            v = Whh[(l * 2 + dir) * 256 + row * 8 + (j ^ m)];
        } else {
            g = r - 96;
            int row = g * 8 + j;
            v = bW[(l * 2 + dir) * 32 + row];
        }
        v *= (g == 2) ? (-2.0f * L2E) : (-L2E);
        sSeg[i] = v;
    }
}

template<int DIR, bool LAST>
__device__ __forceinline__ void run_seg(const float* __restrict__ cur,
                                        float* __restrict__ nxt,
                                        const float* __restrict__ sSeg,
                                        const float* __restrict__ Wout,
                                        float& acc, int el, int j)
{
    const float* ws = &sSeg[j * 100];
    const f32x2* wp = (const f32x2*)ws;

    // ---- phase 1: input-projection weights -> regs, precompute gx[4][10] ----
    f32x2 wx[4][8];
    #pragma unroll
    for (int g = 0; g < 4; ++g)
        #pragma unroll
        for (int p = 0; p < 8; ++p) wx[g][p] = wp[g * 8 + p];
    float bs0 = ws[96], bs1 = ws[97], bs2 = ws[98], bs3 = ws[99];

    float gx[4][10];
    #pragma unroll
    for (int t = 0; t < 10; ++t) {
        const f32x2* xp = (const f32x2*)&cur[(t * EPB + el) * 16];
        f32x2 xv[8];
        #pragma unroll
        for (int p = 0; p < 8; ++p) xv[p] = xp[p];
        f32x2 a0 = {bs0, 0.0f}, a1 = {bs1, 0.0f}, a2 = {bs2, 0.0f}, a3 = {bs3, 0.0f};
        #pragma unroll
        for (int p = 0; p < 8; ++p) {
            PKFMA(a0, wx[0][p], xv[p]);
            PKFMA(a1, wx[1][p], xv[p]);
            PKFMA(a2, wx[2][p], xv[p]);
            PKFMA(a3, wx[3][p], xv[p]);
        }
        gx[0][t] = a0.x + a0.y;
        gx[1][t] = a1.x + a1.y;
        gx[2][t] = a2.x + a2.y;
        gx[3][t] = a3.x + a3.y;
    }

    // ---- phase 2: recurrent weights -> regs (scalar, pre-permuted by j^m) ----
    float wh[4][8];
    #pragma unroll
    for (int g = 0; g < 4; ++g)
        #pragma unroll
        for (int m = 0; m < 8; ++m) wh[g][m] = ws[64 + g * 8 + m];

    // ---- step loop: NO LDS loads in the body (only swizzles + 1 write) ----
    float hn = 0.0f, cst = 0.0f;
    #pragma unroll
    for (int tt = 0; tt < 10; ++tt) {
        const int s = DIR ? (9 - tt) : tt;
        const float h1 = SWZ(hn, 1), h2 = SWZ(hn, 2), h3 = SWZ(hn, 3),
                    h4 = SWZ(hn, 4), h5 = SWZ(hn, 5), h6 = SWZ(hn, 6), h7 = SWZ(hn, 7);

        float g0 = gx[0][s], g1 = gx[1][s], g2 = gx[2][s], g3 = gx[3][s];
        g0 += wh[0][0]*hn + wh[0][1]*h1 + wh[0][2]*h2 + wh[0][3]*h3
            + wh[0][4]*h4 + wh[0][5]*h5 + wh[0][6]*h6 + wh[0][7]*h7;
        g1 += wh[1][0]*hn + wh[1][1]*h1 + wh[1][2]*h2 + wh[1][3]*h3
            + wh[1][4]*h4 + wh[1][5]*h5 + wh[1][6]*h6 + wh[1][7]*h7;
        g2 += wh[2][0]*hn + wh[2][1]*h1 + wh[2][2]*h2 + wh[2][3]*h3
            + wh[2][4]*h4 + wh[2][5]*h5 + wh[2][6]*h6 + wh[2][7]*h7;
        g3 += wh[3][0]*hn + wh[3][1]*h1 + wh[3][2]*h2 + wh[3][3]*h3
            + wh[3][4]*h4 + wh[3][5]*h5 + wh[3][6]*h6 + wh[3][7]*h7;

        // gates are prescaled: sigm(v) = rcp(1+exp2(G)), tanh(v) = 2*rcp(1+exp2(G2)) - 1
        const float ig = __builtin_amdgcn_rcpf(1.0f + __builtin_amdgcn_exp2f(g0));
        const float fg = __builtin_amdgcn_rcpf(1.0f + __builtin_amdgcn_exp2f(g1));
        const float gg = 2.0f * __builtin_amdgcn_rcpf(1.0f + __builtin_amdgcn_exp2f(g2)) - 1.0f;
        const float og = __builtin_amdgcn_rcpf(1.0f + __builtin_amdgcn_exp2f(g3));

        cst = fg * cst + ig * gg;
        const float ec = __builtin_amdgcn_exp2f(-2.0f * L2E * cst);
        const float th = 2.0f * __builtin_amdgcn_rcpf(1.0f + ec) - 1.0f;
        hn = og * th;

        if (LAST) {
            acc += hn * Wout[s * 16 + DIR * 8 + j];
        } else {
            nxt[(s * EPB + el) * 16 + DIR * 8 + j] = hn;
        }
    }
}

__global__ __launch_bounds__(TPB, 2)
void lstm_kernel(const float* __restrict__ x,
                 const float* __restrict__ Wih0,
                 const float* __restrict__ Wih_rest,
                 const float* __restrict__ Whh,
                 const float* __restrict__ bW,
                 const float* __restrict__ Wout,
                 const float* __restrict__ bout,
                 float* __restrict__ out)
{
    __shared__ __align__(16) float bufA[5120];   // [t=10][e=32][16]
    __shared__ __align__(16) float bufB[5120];
    __shared__ __align__(16) float sSeg[800];    // per-segment per-lane weights

    const int tid = threadIdx.x;

    // ---- stage x (coalesced read): x[b][c][t][d] -> bufA[t][e][c*5+d], pad col 15 ----
    const float* xblk = x + (size_t)blockIdx.x * (EPB * 150);
    for (int i = tid; i < EPB * 150; i += TPB) {
        int e = i / 150, r = i % 150;
        int c = r / 50, r2 = r % 50, t = r2 / 5, d = r2 % 5;
        bufA[(t * EPB + e) * 16 + c * 5 + d] = xblk[i];
    }
    for (int i = tid; i < 320; i += TPB) {
        int t = i >> 5, e = i & 31;
        bufA[(t * EPB + e) * 16 + 15] = 0.0f;
    }

    const int lane = tid & 63;
    const int wid  = tid >> 6;
    const int grp  = lane >> 3;
    const int j    = lane & 7;
    const int el   = wid * 8 + grp;

    float acc = 0.0f;

    // layer 0: bufA -> bufB
    build_seg(0, 0, Wih0, Wih_rest, Whh, bW, sSeg, tid);
    __syncthreads();
    run_seg<0, false>(bufA, bufB, sSeg, Wout, acc, el, j);
    __syncthreads();
    build_seg(0, 1, Wih0, Wih_rest, Whh, bW, sSeg, tid);
    __syncthreads();
    run_seg<1, false>(bufA, bufB, sSeg, Wout, acc, el, j);
    __syncthreads();

    // layer 1: bufB -> bufA
    build_seg(1, 0, Wih0, Wih_rest, Whh, bW, sSeg, tid);
    __syncthreads();
    run_seg<0, false>(bufB, bufA, sSeg, Wout, acc, el, j);
    __syncthreads();
    build_seg(1, 1, Wih0, Wih_rest, Whh, bW, sSeg, tid);
    __syncthreads();
    run_seg<1, false>(bufB, bufA, sSeg, Wout, acc, el, j);
    __syncthreads();

    // layer 2: bufA -> acc
    build_seg(2, 0, Wih0, Wih_rest, Whh, bW, sSeg, tid);
    __syncthreads();
    run_seg<0, true>(bufA, bufB, sSeg, Wout, acc, el, j);
    __syncthreads();
    build_seg(2, 1, Wih0, Wih_rest, Whh, bW, sSeg, tid);
    __syncthreads();
    run_seg<1, true>(bufA, bufB, sSeg, Wout, acc, el, j);

    // reduce the 8 lanes of the group -> scalar output
    acc += __shfl_xor(acc, 1);
    acc += __shfl_xor(acc, 2);
    acc += __shfl_xor(acc, 4);
    if (j == 0) {
        out[(size_t)blockIdx.x * EPB + el] = acc + bout[0];
    }
}

extern "C" void kernel_launch(void* const* d_in, const int* in_sizes, int n_in,
                              void* d_out, int out_size, void* d_ws, size_t ws_size,
                              hipStream_t stream) {
    const float* x        = (const float*)d_in[0];
    const float* Wih0     = (const float*)d_in[1];
    const float* Wih_rest = (const float*)d_in[2];
    const float* Whh      = (const float*)d_in[3];
    const float* b        = (const float*)d_in[4];
    const float* Wout     = (const float*)d_in[5];
    const float* bout     = (const float*)d_in[6];
    float* out = (float*)d_out;

    const int nblocks = out_size / EPB;  // 262144 / 32 = 8192
    lstm_kernel<<<nblocks, TPB, 0, stream>>>(x, Wih0, Wih_rest, Whh, b, Wout, bout, out);
}

// Round 5
// 357.220 us; speedup vs baseline: 1.3811x; 1.1722x over previous
//
#include <hip/hip_runtime.h>

#define TPB 256

typedef float f32x2 __attribute__((ext_vector_type(2)));
typedef float f32x4 __attribute__((ext_vector_type(4)));
typedef short s16x8 __attribute__((ext_vector_type(8)));

#define L2E 1.44269504f
#define PKFMA(acc, w, xx) asm("v_pk_fma_f32 %0, %1, %2, %0" : "+v"(acc) : "v"(w), "v"(xx))
#define PKMUL(dst, w, xx) asm("v_pk_mul_f32 %0, %1, %2" : "=v"(dst) : "v"(w), "v"(xx))

// exact two-term bf16 split, packed for MFMA K-slots: low16 = hi-part (k even),
// high16 = lo-part (k odd).  x ~= hi + lo with rel err ~2^-16.
__device__ __forceinline__ unsigned pack_split(float v) {
    unsigned b  = __float_as_uint(v);
    unsigned hi = b >> 16;                                  // trunc bf16
    float    hf = __uint_as_float(b & 0xFFFF0000u);
    unsigned lob = __float_as_uint(v - hf) & 0xFFFF0000u;   // trunc bf16 of residual
    return lob | hi;
}

// Build per-segment weights:
//  sBF[(nt*2+part)*64+lane][4] u32 : B-fragments, value = dup16(part? lo : hi of W_scaled[u][d])
//                                    u = nt*16+(lane&15), d = (lane>>4)*4+ip  (k=2d,2d+1)
//  sWh[j*36 + g*8 + k]            : scaled recurrent weights, per-j stride 36 words (bank-clean)
//  sBias[u]                       : scaled bias
__device__ __forceinline__ void build_seg(int l, int dir,
        const float* __restrict__ Wih0, const float* __restrict__ Wih_rest,
        const float* __restrict__ Whh,  const float* __restrict__ bW,
        unsigned* __restrict__ sBF, float* __restrict__ sWh,
        float* __restrict__ sBias, int tid)
{
    const int seg = l * 2 + dir;
    {   // B-fragments: each thread builds 4 u32 for one (nt, part, lane)
        const int lane_ = tid & 63, part = (tid >> 6) & 1, nt = tid >> 7;
        const int u  = nt * 16 + (lane_ & 15);
        const float sc = ((u >> 3) == 2) ? (-2.0f * L2E) : (-L2E);
        #pragma unroll
        for (int ip = 0; ip < 4; ++ip) {
            const int d = (lane_ >> 4) * 4 + ip;
            float w;
            if (l == 0) w = (d < 15) ? Wih0[dir * 480 + u * 15 + d] : 0.0f;
            else        w = Wih_rest[((l - 1) * 2 + dir) * 512 + u * 16 + d];
            w *= sc;
            unsigned b = __float_as_uint(w);
            unsigned v16;
            if (part == 0) v16 = b >> 16;
            else {
                float hf = __uint_as_float(b & 0xFFFF0000u);
                v16 = __float_as_uint(w - hf) >> 16;
            }
            sBF[((nt * 2 + part) * 64 + lane_) * 4 + ip] = v16 | (v16 << 16);
        }
    }
    {   // recurrent weights (one value per thread)
        const int jj = tid >> 5, rr = tid & 31;
        const float sc = ((rr >> 3) == 2) ? (-2.0f * L2E) : (-L2E);
        const int u = (rr >> 3) * 8 + jj;
        sWh[jj * 36 + rr] = sc * Whh[seg * 256 + u * 8 + (rr & 7)];
    }
    if (tid < 32) {
        const float sc = ((tid >> 3) == 2) ? (-2.0f * L2E) : (-L2E);
        sBias[tid] = sc * bW[seg * 32 + tid];
    }
}

// One (layer, direction) segment for one wave's 8 elements.
// Phase 1: projection gx[4][10] via 4 MFMAs/M-tile (split-bf16 exact).
// Phase 2: serial recurrence, h exchanged through wave-private LDS.
template<int DIR, bool LAST>
__device__ __forceinline__ void run_seg(const unsigned* __restrict__ XSin,
                                        unsigned* __restrict__ XSout,
                                        const unsigned* __restrict__ sBF,
                                        const float* __restrict__ sWh,
                                        const float* __restrict__ sBias,
                                        const float* __restrict__ sWout,
                                        float* __restrict__ G2,
                                        float* __restrict__ sH,
                                        float& accOut, int lane, int wid)
{
    const int r   = lane & 15;
    const int kb  = lane >> 4;          // K-block 0..3
    const int grp = lane >> 3;          // element within wave
    const int j   = lane & 7;           // hidden unit owned in phase 2
    const int elg = wid * 8 + grp;

    // B fragments (resident in 16 VGPRs, HW-reused across all M-tiles)
    s16x8 Bf00 = *(const s16x8*)&sBF[(0 * 64 + lane) * 4];
    s16x8 Bf01 = *(const s16x8*)&sBF[(1 * 64 + lane) * 4];
    s16x8 Bf10 = *(const s16x8*)&sBF[(2 * 64 + lane) * 4];
    s16x8 Bf11 = *(const s16x8*)&sBF[(3 * 64 + lane) * 4];
    const float bs0 = sBias[r];
    const float bs1 = sBias[16 + r];

    // A-frag word index: row R = 16m + r -> t = R>>3, el = R&7; +m -> +1024 words
    const int AI0 = ((r >> 3) * 32 + wid * 8 + (r & 7)) * 16 + kb * 4;
    // scatter/gather bases in G2 (per-wave region, stride 36 words per el)
    const int tloc  = kb >> 1;
    const int base7 = (kb & 1) * 4;
    const int SBW = wid * 576 + tloc * 288 + base7 * 36 + r;
    const int GBW = wid * 576 + grp * 36 + j;

    float gx[4][10];
    #pragma unroll
    for (int m = 0; m < 5; ++m) {
        s16x8 A = *(const s16x8*)&XSin[AI0 + m * 1024];
        f32x4 acc0 = {bs0, bs0, bs0, bs0};
        f32x4 acc1 = {bs1, bs1, bs1, bs1};
        acc0 = __builtin_amdgcn_mfma_f32_16x16x32_bf16(A, Bf00, acc0, 0, 0, 0);
        acc0 = __builtin_amdgcn_mfma_f32_16x16x32_bf16(A, Bf01, acc0, 0, 0, 0);
        acc1 = __builtin_amdgcn_mfma_f32_16x16x32_bf16(A, Bf10, acc1, 0, 0, 0);
        acc1 = __builtin_amdgcn_mfma_f32_16x16x32_bf16(A, Bf11, acc1, 0, 0, 0);
        #pragma unroll
        for (int q = 0; q < 4; ++q) {           // rows R = 16m + kb*4 + q
            G2[SBW + q * 36]      = acc0[q];    // units 0..15
            G2[SBW + q * 36 + 16] = acc1[q];    // units 16..31
        }
        #pragma unroll
        for (int t2 = 0; t2 < 2; ++t2)
            #pragma unroll
            for (int g = 0; g < 4; ++g)
                gx[g][2 * m + t2] = G2[GBW + t2 * 288 + g * 8];
    }

    // recurrent weights as f32x2 pairs (32 VGPRs)
    f32x2 whp[16];
    #pragma unroll
    for (int g = 0; g < 4; ++g)
        #pragma unroll
        for (int kp = 0; kp < 4; ++kp)
            whp[g * 4 + kp] = *(const f32x2*)&sWh[j * 36 + g * 8 + kp * 2];

    float cst = 0.0f, hn = 0.0f;
    const int hbase = wid * 64 + grp * 8;
    #pragma unroll
    for (int tt = 0; tt < 10; ++tt) {
        const int s = DIR ? (9 - tt) : tt;
        float g0 = gx[0][s], g1 = gx[1][s], g2v = gx[2][s], g3 = gx[3][s];
        if (tt > 0) {
            f32x2 h01 = *(const f32x2*)&sH[hbase];
            f32x2 h23 = *(const f32x2*)&sH[hbase + 2];
            f32x2 h45 = *(const f32x2*)&sH[hbase + 4];
            f32x2 h67 = *(const f32x2*)&sH[hbase + 6];
            f32x2 a0, a1, a2, a3;
            PKMUL(a0, whp[0],  h01); PKFMA(a0, whp[1],  h23); PKFMA(a0, whp[2],  h45); PKFMA(a0, whp[3],  h67);
            PKMUL(a1, whp[4],  h01); PKFMA(a1, whp[5],  h23); PKFMA(a1, whp[6],  h45); PKFMA(a1, whp[7],  h67);
            PKMUL(a2, whp[8],  h01); PKFMA(a2, whp[9],  h23); PKFMA(a2, whp[10], h45); PKFMA(a2, whp[11], h67);
            PKMUL(a3, whp[12], h01); PKFMA(a3, whp[13], h23); PKFMA(a3, whp[14], h45); PKFMA(a3, whp[15], h67);
            g0 += a0.x + a0.y; g1 += a1.x + a1.y;
            g2v += a2.x + a2.y; g3 += a3.x + a3.y;
        }
        // weights prescaled: sigm = rcp(1+exp2(G)), tanh = 2*rcp(1+exp2(G2)) - 1
        const float ig = __builtin_amdgcn_rcpf(1.0f + __builtin_amdgcn_exp2f(g0));
        const float fg = __builtin_amdgcn_rcpf(1.0f + __builtin_amdgcn_exp2f(g1));
        const float gg = 2.0f * __builtin_amdgcn_rcpf(1.0f + __builtin_amdgcn_exp2f(g2v)) - 1.0f;
        const float og = __builtin_amdgcn_rcpf(1.0f + __builtin_amdgcn_exp2f(g3));
        cst = fg * cst + ig * gg;
        const float ec = __builtin_amdgcn_exp2f(-2.0f * L2E * cst);
        const float th = 2.0f * __builtin_amdgcn_rcpf(1.0f + ec) - 1.0f;
        hn = og * th;

        if (tt < 9) sH[hbase + j] = hn;
        if (LAST) accOut += hn * sWout[s * 16 + DIR * 8 + j];
        else      XSout[((s * 32 + elg) << 4) + DIR * 8 + j] = pack_split(hn);
    }
}

__global__ __launch_bounds__(TPB, 2)
void lstm_kernel(const float* __restrict__ x,
                 const float* __restrict__ Wih0,
                 const float* __restrict__ Wih_rest,
                 const float* __restrict__ Whh,
                 const float* __restrict__ bW,
                 const float* __restrict__ Wout,
                 const float* __restrict__ bout,
                 float* __restrict__ out)
{
    __shared__ __align__(16) unsigned XA[5120];   // [t][elg][16] split-packed, 20KB
    __shared__ __align__(16) unsigned XB[5120];   // 20KB
    __shared__ __align__(16) float    G2[2304];   // per-wave MFMA-out bounce, 9KB
    __shared__ __align__(16) float    sH[256];    // per-wave h exchange
    __shared__ __align__(16) unsigned sBF[1024];  // B-fragments, 4KB
    __shared__ __align__(16) float    sWh[288];
    __shared__             float      sBias[32];
    __shared__             float      sWoutS[160];

    const int tid = threadIdx.x;
    if (tid < 160) sWoutS[tid] = Wout[tid];

    // stage x (coalesced): x[b][c][t][d] -> XA[t][e][c*5+d] split-packed; pad slot 15
    const float* xblk = x + (size_t)blockIdx.x * (32 * 150);
    for (int i = tid; i < 4800; i += TPB) {
        int e = i / 150, rr = i % 150;
        int c = rr / 50, r2 = rr % 50, t = r2 / 5, d = r2 % 5;
        XA[((t * 32 + e) << 4) + c * 5 + d] = pack_split(xblk[i]);
    }
    for (int i = tid; i < 320; i += TPB) {
        int t = i >> 5, e = i & 31;
        XA[((t * 32 + e) << 4) + 15] = 0u;
    }
    build_seg(0, 0, Wih0, Wih_rest, Whh, bW, sBF, sWh, sBias, tid);

    const int lane = tid & 63, wid = tid >> 6;
    float accOut = 0.0f;

    __syncthreads();
    run_seg<0, false>(XA, XB, sBF, sWh, sBias, sWoutS, G2, sH, accOut, lane, wid);
    __syncthreads();
    build_seg(0, 1, Wih0, Wih_rest, Whh, bW, sBF, sWh, sBias, tid);
    __syncthreads();
    run_seg<1, false>(XA, XB, sBF, sWh, sBias, sWoutS, G2, sH, accOut, lane, wid);
    __syncthreads();
    build_seg(1, 0, Wih0, Wih_rest, Whh, bW, sBF, sWh, sBias, tid);
    __syncthreads();
    run_seg<0, false>(XB, XA, sBF, sWh, sBias, sWoutS, G2, sH, accOut, lane, wid);
    __syncthreads();
    build_seg(1, 1, Wih0, Wih_rest, Whh, bW, sBF, sWh, sBias, tid);
    __syncthreads();
    run_seg<1, false>(XB, XA, sBF, sWh, sBias, sWoutS, G2, sH, accOut, lane, wid);
    __syncthreads();
    build_seg(2, 0, Wih0, Wih_rest, Whh, bW, sBF, sWh, sBias, tid);
    __syncthreads();
    run_seg<0, true>(XA, XB, sBF, sWh, sBias, sWoutS, G2, sH, accOut, lane, wid);
    __syncthreads();
    build_seg(2, 1, Wih0, Wih_rest, Whh, bW, sBF, sWh, sBias, tid);
    __syncthreads();
    run_seg<1, true>(XA, XB, sBF, sWh, sBias, sWoutS, G2, sH, accOut, lane, wid);

    accOut += __shfl_xor(accOut, 1);
    accOut += __shfl_xor(accOut, 2);
    accOut += __shfl_xor(accOut, 4);
    if ((lane & 7) == 0)
        out[(size_t)blockIdx.x * 32 + wid * 8 + (lane >> 3)] = accOut + bout[0];
}

extern "C" void kernel_launch(void* const* d_in, const int* in_sizes, int n_in,
                              void* d_out, int out_size, void* d_ws, size_t ws_size,
                              hipStream_t stream) {
    const float* x        = (const float*)d_in[0];
    const float* Wih0     = (const float*)d_in[1];
    const float* Wih_rest = (const float*)d_in[2];
    const float* Whh      = (const float*)d_in[3];
    const float* b        = (const float*)d_in[4];
    const float* Wout     = (const float*)d_in[5];
    const float* bout     = (const float*)d_in[6];
    float* out = (float*)d_out;

    const int nblocks = out_size / 32;  // 8192
    lstm_kernel<<<nblocks, TPB, 0, stream>>>(x, Wih0, Wih_rest, Whh, b, Wout, bout, out);
}

// Round 6
// 295.145 us; speedup vs baseline: 1.6716x; 1.2103x over previous
//
#include <hip/hip_runtime.h>

#define TPB 256
#define L2E 1.44269504f

typedef float f32x4 __attribute__((ext_vector_type(4)));
typedef short s16x8 __attribute__((ext_vector_type(8)));

// lane->lane XOR shuffle within 32-lane halves (BitMode: xor<<10 | and 0x1F)
#define SWZ(v, m) __int_as_float(__builtin_amdgcn_ds_swizzle(__float_as_int(v), ((m) << 10) | 31))

// exact two-term bf16 split packed into one u32: low16 = hi-part (even k), high16 = lo-part (odd k)
__device__ __forceinline__ unsigned pack_split(float v) {
    unsigned b  = __float_as_uint(v);
    unsigned hi = b >> 16;
    float    hf = __uint_as_float(b & 0xFFFF0000u);
    unsigned lob = __float_as_uint(v - hf) & 0xFFFF0000u;
    return lob | hi;
}

// ---------------- prep kernel: build all segment weights once into d_ws ----------------
// wsBF  [seg][frag(4)][lane(64)][4] u32 : B-fragments (frag = nt*2+part), dup16 of hi/lo of W_scaled
// wsWH  [seg][j(8)][g*8+m]            : s_g * Whh[g*8+j][j^m]  (pre-permuted for XOR swizzles)
// wsBIAS[seg][u(32)]                  : s_g * bias[u]
__global__ void prep_kernel(const float* __restrict__ Wih0,
                            const float* __restrict__ Wih_rest,
                            const float* __restrict__ Whh,
                            const float* __restrict__ bW,
                            unsigned* __restrict__ wsBF,
                            float* __restrict__ wsWH,
                            float* __restrict__ wsBIAS)
{
    const int tid = threadIdx.x;
    for (int seg = 0; seg < 6; ++seg) {
        const int l = seg >> 1, dir = seg & 1;
        {   // B-fragments
            const int lane_ = tid & 63, part = (tid >> 6) & 1, nt = tid >> 7;
            const int u = nt * 16 + (lane_ & 15);
            const float sc = ((u >> 3) == 2) ? (-2.0f * L2E) : (-L2E);
            #pragma unroll
            for (int ip = 0; ip < 4; ++ip) {
                const int d = (lane_ >> 4) * 4 + ip;
                float w;
                if (l == 0) w = (d < 15) ? Wih0[dir * 480 + u * 15 + d] : 0.0f;
                else        w = Wih_rest[((l - 1) * 2 + dir) * 512 + u * 16 + d];
                w *= sc;
                unsigned b = __float_as_uint(w);
                unsigned v16;
                if (part == 0) v16 = b >> 16;
                else {
                    float hf = __uint_as_float(b & 0xFFFF0000u);
                    v16 = __float_as_uint(w - hf) >> 16;
                }
                wsBF[seg * 4096 + ((nt * 2 + part) * 64 + lane_) * 4 + ip] = v16 | (v16 << 16);
            }
        }
        {   // recurrent weights, pre-permuted for swizzle exchange
            const int jj = tid >> 5, rr = tid & 31, g = rr >> 3, m = rr & 7;
            const float sc = (g == 2) ? (-2.0f * L2E) : (-L2E);
            wsWH[seg * 256 + jj * 32 + rr] = sc * Whh[seg * 256 + (g * 8 + jj) * 8 + (jj ^ m)];
        }
        if (tid < 32) {
            const float sc = ((tid >> 3) == 2) ? (-2.0f * L2E) : (-L2E);
            wsBIAS[seg * 32 + tid] = sc * bW[seg * 32 + tid];
        }
    }
}

// ---------------- main kernel ----------------
// X layout: [t(10)][el(32)][17 words] split-packed u32 (slot 16 unused padding)
template<int DIR, bool LAST>
__device__ __forceinline__ void run_seg(const unsigned* __restrict__ XSin,
                                        unsigned* __restrict__ XSout,
                                        const unsigned* __restrict__ bfSeg,
                                        const float* __restrict__ whSeg,
                                        const float* __restrict__ biasSeg,
                                        const float* __restrict__ Wout,
                                        float* __restrict__ G2,
                                        float& accOut, int lane, int wid)
{
    const int r   = lane & 15;
    const int kb  = lane >> 4;
    const int grp = lane >> 3;
    const int j   = lane & 7;
    const int elg = wid * 8 + grp;

    // B fragments + bias from global (L1/L2-hot, same 24KB for all blocks)
    s16x8 Bf00 = *(const s16x8*)&bfSeg[(0 * 64 + lane) * 4];
    s16x8 Bf01 = *(const s16x8*)&bfSeg[(1 * 64 + lane) * 4];
    s16x8 Bf10 = *(const s16x8*)&bfSeg[(2 * 64 + lane) * 4];
    s16x8 Bf11 = *(const s16x8*)&bfSeg[(3 * 64 + lane) * 4];
    const float bs0 = biasSeg[r];
    const float bs1 = biasSeg[16 + r];

    // A-frag word index: row r -> (el = r&7, tpar = r>>3); tile m -> t = 2m+tpar
    const int AI0 = ((r >> 3) * 32 + wid * 8 + (r & 7)) * 17 + kb * 4;
    const int SBW = wid * 576 + (kb >> 1) * 288 + (kb & 1) * 4 * 36 + r;
    const int GBW = wid * 576 + grp * 36 + j;

    float gx[4][10];
    #pragma unroll
    for (int m = 0; m < 5; ++m) {
        s16x8 A = *(const s16x8*)&XSin[AI0 + m * 1088];   // 2*32*17 words per 2 timesteps
        f32x4 acc0 = {bs0, bs0, bs0, bs0};
        f32x4 acc1 = {bs1, bs1, bs1, bs1};
        acc0 = __builtin_amdgcn_mfma_f32_16x16x32_bf16(A, Bf00, acc0, 0, 0, 0);
        acc0 = __builtin_amdgcn_mfma_f32_16x16x32_bf16(A, Bf01, acc0, 0, 0, 0);
        acc1 = __builtin_amdgcn_mfma_f32_16x16x32_bf16(A, Bf10, acc1, 0, 0, 0);
        acc1 = __builtin_amdgcn_mfma_f32_16x16x32_bf16(A, Bf11, acc1, 0, 0, 0);
        #pragma unroll
        for (int q = 0; q < 4; ++q) {           // rows 4kb+q -> (el=(kb&1)*4+q, tpar=kb>>1)
            G2[SBW + q * 36]      = acc0[q];    // units 0..15
            G2[SBW + q * 36 + 16] = acc1[q];    // units 16..31
        }
        #pragma unroll
        for (int t2 = 0; t2 < 2; ++t2)
            #pragma unroll
            for (int g = 0; g < 4; ++g)
                gx[g][2 * m + t2] = G2[GBW + t2 * 288 + g * 8];
    }

    // recurrent weights -> regs (plain loads; AGPR-parking is OK, scalar FMA reads them directly)
    float wh[32];
    #pragma unroll
    for (int q = 0; q < 8; ++q)
        *(f32x4*)&wh[q * 4] = *(const f32x4*)&whSeg[j * 32 + q * 4];

    float cst = 0.0f, hn = 0.0f;
    #pragma unroll
    for (int tt = 0; tt < 10; ++tt) {
        const int s = DIR ? (9 - tt) : tt;
        float g0 = gx[0][s], g1 = gx[1][s], g2v = gx[2][s], g3 = gx[3][s];
        if (tt > 0) {
            const float h1 = SWZ(hn, 1), h2 = SWZ(hn, 2), h3 = SWZ(hn, 3),
                        h4 = SWZ(hn, 4), h5 = SWZ(hn, 5), h6 = SWZ(hn, 6), h7 = SWZ(hn, 7);
            g0 = fmaf(wh[0], hn, g0);  g0 = fmaf(wh[1], h1, g0);
            g0 = fmaf(wh[2], h2, g0);  g0 = fmaf(wh[3], h3, g0);
            g0 = fmaf(wh[4], h4, g0);  g0 = fmaf(wh[5], h5, g0);
            g0 = fmaf(wh[6], h6, g0);  g0 = fmaf(wh[7], h7, g0);
            g1 = fmaf(wh[8], hn, g1);  g1 = fmaf(wh[9], h1, g1);
            g1 = fmaf(wh[10], h2, g1); g1 = fmaf(wh[11], h3, g1);
            g1 = fmaf(wh[12], h4, g1); g1 = fmaf(wh[13], h5, g1);
            g1 = fmaf(wh[14], h6, g1); g1 = fmaf(wh[15], h7, g1);
            g2v = fmaf(wh[16], hn, g2v); g2v = fmaf(wh[17], h1, g2v);
            g2v = fmaf(wh[18], h2, g2v); g2v = fmaf(wh[19], h3, g2v);
            g2v = fmaf(wh[20], h4, g2v); g2v = fmaf(wh[21], h5, g2v);
            g2v = fmaf(wh[22], h6, g2v); g2v = fmaf(wh[23], h7, g2v);
            g3 = fmaf(wh[24], hn, g3);  g3 = fmaf(wh[25], h1, g3);
            g3 = fmaf(wh[26], h2, g3);  g3 = fmaf(wh[27], h3, g3);
            g3 = fmaf(wh[28], h4, g3);  g3 = fmaf(wh[29], h5, g3);
            g3 = fmaf(wh[30], h6, g3);  g3 = fmaf(wh[31], h7, g3);
        }
        // weights prescaled: sigm = rcp(1+exp2(G)), tanh = 2*rcp(1+exp2(G2)) - 1
        const float ig = __builtin_amdgcn_rcpf(1.0f + __builtin_amdgcn_exp2f(g0));
        const float fg = __builtin_amdgcn_rcpf(1.0f + __builtin_amdgcn_exp2f(g1));
        const float gg = 2.0f * __builtin_amdgcn_rcpf(1.0f + __builtin_amdgcn_exp2f(g2v)) - 1.0f;
        const float og = __builtin_amdgcn_rcpf(1.0f + __builtin_amdgcn_exp2f(g3));
        cst = fg * cst + ig * gg;
        const float ec = __builtin_amdgcn_exp2f(-2.0f * L2E * cst);
        const float th = 2.0f * __builtin_amdgcn_rcpf(1.0f + ec) - 1.0f;
        hn = og * th;

        if (LAST) accOut += hn * Wout[s * 16 + DIR * 8 + j];
        else      XSout[(s * 32 + elg) * 17 + DIR * 8 + j] = pack_split(hn);
    }
}

__global__ __launch_bounds__(TPB, 3)
void lstm_kernel(const float* __restrict__ x,
                 const unsigned* __restrict__ wsBF,
                 const float* __restrict__ wsWH,
                 const float* __restrict__ wsBIAS,
                 const float* __restrict__ Wout,
                 const float* __restrict__ bout,
                 float* __restrict__ out)
{
    __shared__ __align__(16) unsigned XA[5440];   // [t][el][17], 21.25KB
    __shared__ __align__(16) unsigned XB[5440];
    __shared__ __align__(16) float    G2[2304];   // per-wave MFMA bounce, 9KB

    const int tid  = threadIdx.x;
    const int lane = tid & 63, wid = tid >> 6;

    // per-wave x staging (coalesced: each wave reads its own 1200 contiguous floats)
    const float* xw = x + (size_t)blockIdx.x * 4800 + wid * 1200;
    for (int i = lane; i < 1200; i += 64) {
        int e = wid * 8 + i / 150, rr = i % 150;
        int c = rr / 50, r2 = rr % 50, t = r2 / 5, d = r2 % 5;
        XA[(t * 32 + e) * 17 + c * 5 + d] = pack_split(xw[i]);
    }
    for (int i = lane; i < 80; i += 64) {         // zero slot 15 (layer-0 input is 15-dim)
        int t = i >> 3, e = wid * 8 + (i & 7);
        XA[(t * 32 + e) * 17 + 15] = 0u;
    }
    // NO __syncthreads anywhere: all LDS regions are wave-private, waves drift freely.

    float accOut = 0.0f;
    run_seg<0, false>(XA, XB, wsBF + 0 * 4096, wsWH + 0 * 256, wsBIAS + 0 * 32, Wout, G2, accOut, lane, wid);
    run_seg<1, false>(XA, XB, wsBF + 1 * 4096, wsWH + 1 * 256, wsBIAS + 1 * 32, Wout, G2, accOut, lane, wid);
    run_seg<0, false>(XB, XA, wsBF + 2 * 4096, wsWH + 2 * 256, wsBIAS + 2 * 32, Wout, G2, accOut, lane, wid);
    run_seg<1, false>(XB, XA, wsBF + 3 * 4096, wsWH + 3 * 256, wsBIAS + 3 * 32, Wout, G2, accOut, lane, wid);
    run_seg<0, true >(XA, XB, wsBF + 4 * 4096, wsWH + 4 * 256, wsBIAS + 4 * 32, Wout, G2, accOut, lane, wid);
    run_seg<1, true >(XA, XB, wsBF + 5 * 4096, wsWH + 5 * 256, wsBIAS + 5 * 32, Wout, G2, accOut, lane, wid);

    accOut += __shfl_xor(accOut, 1);
    accOut += __shfl_xor(accOut, 2);
    accOut += __shfl_xor(accOut, 4);
    if ((lane & 7) == 0)
        out[(size_t)blockIdx.x * 32 + wid * 8 + (lane >> 3)] = accOut + bout[0];
}

extern "C" void kernel_launch(void* const* d_in, const int* in_sizes, int n_in,
                              void* d_out, int out_size, void* d_ws, size_t ws_size,
                              hipStream_t stream) {
    const float* x        = (const float*)d_in[0];
    const float* Wih0     = (const float*)d_in[1];
    const float* Wih_rest = (const float*)d_in[2];
    const float* Whh      = (const float*)d_in[3];
    const float* b        = (const float*)d_in[4];
    const float* Wout     = (const float*)d_in[5];
    const float* bout     = (const float*)d_in[6];
    float* out = (float*)d_out;

    unsigned* wsBF   = (unsigned*)d_ws;                  // 6*4096 u32 = 96KB
    float*    wsWH   = (float*)d_ws + 6 * 4096;          // 6*256 f32
    float*    wsBIAS = (float*)d_ws + 6 * 4096 + 6 * 256;// 6*32 f32

    prep_kernel<<<1, TPB, 0, stream>>>(Wih0, Wih_rest, Whh, b, wsBF, wsWH, wsBIAS);

    const int nblocks = out_size / 32;  // 8192
    lstm_kernel<<<nblocks, TPB, 0, stream>>>(x, wsBF, wsWH, wsBIAS, Wout, bout, out);
}